// Round 5
// baseline (24916.876 us; speedup 1.0000x reference)
//
#include <hip/hip_runtime.h>
#include <stdint.h>

typedef __attribute__((ext_vector_type(8))) short bf16x8;
typedef __attribute__((ext_vector_type(4))) float f32x4;
typedef unsigned long long u64t;

__device__ inline unsigned short f2bf(float x){
    unsigned u = __float_as_uint(x);
    unsigned r = (u + 0x7fffu + ((u >> 16) & 1u)) >> 16;
    return (unsigned short)r;
}
__device__ inline float bf2f(unsigned short s){
    return __uint_as_float(((unsigned)s) << 16);
}

// ============================ NEW PATH =====================================
// ws layout (new path):
//   [0, 0x20000000)        xW[t*32+b][2048] f32 (512 MB)
//   [0x20000000, +2MB)     Wh frags [cg32][kb16][ct4][lane64][8] shorts
//   +0x200000 Wl, +0x400000 Uh, +0x600000 Ul
//   [0x20800000, +128KB)   hbuf[buf2][bt2][kb16][lane64][j8] u32 (bf16hi|lo<<16)
//   [0x20820000, 256B)     done[bt2][cg32] u32
//   [0x20821000, 32B)      ecnt[8]; +32: elected u32
#define NEED_WS 0x20822000ull

__global__ void prep_new(const float* __restrict__ W, const float* __restrict__ U,
                         const float* __restrict__ h0,
                         unsigned short* __restrict__ Wh, unsigned short* __restrict__ Wl,
                         unsigned short* __restrict__ Uh, unsigned short* __restrict__ Ul,
                         unsigned* __restrict__ hbuf){
    int idx = blockIdx.x * blockDim.x + threadIdx.x;
    int stride = gridDim.x * blockDim.x;
    const int total = 2 * 512 * 2048;
    for (int i = idx; i < total; i += stride){
        int mat = i >> 20;
        int r = i & 1048575;
        int k = r >> 11;
        int col = r & 2047;
        float v = (mat ? U : W)[(size_t)k * 2048 + col];
        unsigned short hi = f2bf(v);
        unsigned short lo = f2bf(v - bf2f(hi));
        int cg = (col & 511) >> 4;
        int hc = col & 15;
        int g  = col >> 9;
        int kb = k >> 5;
        int kgrp = (k >> 3) & 3;
        int j = k & 7;
        size_t dst = (size_t)cg * 32768 + (size_t)kb * 2048 + (size_t)g * 512
                   + (size_t)(kgrp * 16 + hc) * 8 + j;
        if (mat){ Uh[dst] = hi; Ul[dst] = lo; } else { Wh[dst] = hi; Wl[dst] = lo; }
    }
    // h0 -> hbuf[0][bt][kb][lane][j] frag-packed
    for (int i = idx; i < 32 * 512; i += stride){
        int b = i >> 9;
        int k = i & 511;
        float v = h0[i];
        unsigned short hi = f2bf(v);
        unsigned short lo = f2bf(v - bf2f(hi));
        int bt = b >> 4, cb = b & 15;
        int kb = k >> 5, kgrp = (k >> 3) & 3, j = k & 7;
        size_t dst = (size_t)bt * 8192 + (size_t)kb * 512 + (size_t)(kgrp * 16 + cb) * 8 + j;
        hbuf[dst] = (unsigned)hi | ((unsigned)lo << 16);
    }
}

// xW = src @ W, M = t*32+b (65536), N = 2048, K = 512, hi/lo 3-pass
__global__ __launch_bounds__(256) void xw_gemm(
        const float* __restrict__ src,
        const unsigned short* __restrict__ Wh, const unsigned short* __restrict__ Wl,
        float* __restrict__ xW){
    const int bid = blockIdx.x;          // 16384 = mtile(512) * cg(32)
    const int mtile = bid >> 5;
    const int cg = bid & 31;
    const int tid = threadIdx.x;
    const int lane = tid & 63;
    const int w = tid >> 6;              // wave = t offset 0..3
    const int t = mtile * 4 + w;
    const int lc = lane & 15;
    const int kgrp = lane >> 4;

    const uint4* WhF = reinterpret_cast<const uint4*>(Wh) + (size_t)cg * 4096;
    const uint4* WlF = reinterpret_cast<const uint4*>(Wl) + (size_t)cg * 4096;

    f32x4 acc[2][4];
    #pragma unroll
    for (int bt = 0; bt < 2; bt++)
        #pragma unroll
        for (int ct = 0; ct < 4; ct++)
            #pragma unroll
            for (int r = 0; r < 4; r++) acc[bt][ct][r] = 0.f;

    for (int kb = 0; kb < 16; kb++){
        bf16x8 ah[2], al[2];
        #pragma unroll
        for (int bt = 0; bt < 2; bt++){
            const float* xp = src + ((size_t)(bt * 16 + lc) * 2048 + t) * 512 + kb * 32 + kgrp * 8;
            float xv[8];
            *reinterpret_cast<float4*>(&xv[0]) = *reinterpret_cast<const float4*>(xp);
            *reinterpret_cast<float4*>(&xv[4]) = *reinterpret_cast<const float4*>(xp + 4);
            #pragma unroll
            for (int j = 0; j < 8; j++){
                unsigned short hi = f2bf(xv[j]);
                ah[bt][j] = (short)hi;
                al[bt][j] = (short)f2bf(xv[j] - bf2f(hi));
            }
        }
        #pragma unroll
        for (int ct = 0; ct < 4; ct++){
            uint4 bh4 = WhF[kb * 256 + ct * 64 + lane];
            uint4 bl4 = WlF[kb * 256 + ct * 64 + lane];
            bf16x8 bh = *reinterpret_cast<bf16x8*>(&bh4);
            bf16x8 bl = *reinterpret_cast<bf16x8*>(&bl4);
            #pragma unroll
            for (int bt = 0; bt < 2; bt++){
                acc[bt][ct] = __builtin_amdgcn_mfma_f32_16x16x32_bf16(ah[bt], bh, acc[bt][ct], 0, 0, 0);
                acc[bt][ct] = __builtin_amdgcn_mfma_f32_16x16x32_bf16(ah[bt], bl, acc[bt][ct], 0, 0, 0);
                acc[bt][ct] = __builtin_amdgcn_mfma_f32_16x16x32_bf16(al[bt], bh, acc[bt][ct], 0, 0, 0);
            }
        }
    }
    #pragma unroll
    for (int bt = 0; bt < 2; bt++)
        #pragma unroll
        for (int ct = 0; ct < 4; ct++)
            #pragma unroll
            for (int r = 0; r < 4; r++){
                int row_b = bt * 16 + kgrp * 4 + r;
                xW[((size_t)t * 32 + row_b) * 2048 + ct * 512 + cg * 16 + lc] = acc[bt][ct][r];
            }
}

// intra-XCD sc0 helpers (bypass L1, coherent through the XCD's L2)
__device__ inline void st_sc0(unsigned* p, unsigned v){
    asm volatile("global_store_dword %0, %1, off sc0" :: "v"(p), "v"(v) : "memory");
}

__global__ __launch_bounds__(256, 2) void lstm_scan_xcd(
        const float* __restrict__ bias, const float* __restrict__ c0,
        const unsigned short* __restrict__ Uh, const unsigned short* __restrict__ Ul,
        unsigned* __restrict__ hbuf, unsigned* __restrict__ done,
        unsigned* __restrict__ ecnt, unsigned* __restrict__ elected,
        const float* __restrict__ xW, float* __restrict__ out){
    // ---- XCD election: first XCD to accumulate 64 WGs wins ----
    __shared__ unsigned s_my;
    if (threadIdx.x == 0){
        unsigned xcc;
        asm volatile("s_getreg_b32 %0, hwreg(HW_REG_XCC_ID)" : "=s"(xcc));
        xcc &= 7u;
        unsigned n = atomicAdd(&ecnt[xcc], 1u);
        if (n == 63u) atomicCAS(elected, 0xFFFFFFFFu, xcc);
        unsigned e;
        do {
            e = __hip_atomic_load(elected, __ATOMIC_RELAXED, __HIP_MEMORY_SCOPE_AGENT);
        } while (e == 0xFFFFFFFFu);
        s_my = (e == xcc && n < 64u) ? n : 0xFFFFFFFFu;
    }
    __syncthreads();
    const unsigned myid = s_my;
    if (myid == 0xFFFFFFFFu) return;

    const int cg = (int)(myid >> 1);     // 0..31: h-cols [cg*16, +16)
    const int bt = (int)(myid & 1);      // batch tile
    const int tid  = threadIdx.x;
    const int lane = tid & 63;
    const int kq   = tid >> 6;           // wave = K quarter (128 k)
    const int lc   = lane & 15;
    const int kgrp = lane >> 4;

    __shared__ float z_lds[4][16][65];

    // ---- U fragments, register-resident: [kb-in-quarter][ct] hi/lo ----
    const uint4* UhF = reinterpret_cast<const uint4*>(Uh) + (size_t)cg * 4096;
    const uint4* UlF = reinterpret_cast<const uint4*>(Ul) + (size_t)cg * 4096;
    bf16x8 uh[4][4], ul[4][4];
    #pragma unroll
    for (int i = 0; i < 4; i++){
        int kb = kq * 4 + i;
        #pragma unroll
        for (int ct = 0; ct < 4; ct++){
            uint4 a = UhF[kb * 256 + ct * 64 + lane];
            uint4 b2 = UlF[kb * 256 + ct * 64 + lane];
            uh[i][ct] = *reinterpret_cast<bf16x8*>(&a);
            ul[i][ct] = *reinterpret_cast<bf16x8*>(&b2);
        }
    }

    // ---- gate cell: one per thread ----
    const int cb  = tid >> 4;            // 0..15 row within bt
    const int chc = tid & 15;
    const int b   = bt * 16 + cb;        // global batch row
    const int col = cg * 16 + chc;       // global h col
    float c_state = c0[(size_t)b * 512 + col];
    float bias_g[4];
    #pragma unroll
    for (int g = 0; g < 4; g++) bias_g[g] = bias[g * 512 + col];

    // producer store address (frag-packed hbuf), per parity
    const int kb_p = col >> 5, kgp = (col >> 3) & 3, jp = col & 7;
    unsigned* hw0 = hbuf + (size_t)(0 * 2 + bt) * 8192 + (size_t)kb_p * 512 + (size_t)(kgp * 16 + cb) * 8 + jp;
    unsigned* hw1 = hw0 + 2 * 8192;

    f32x4 acc[4];
    #pragma unroll
    for (int ct = 0; ct < 4; ct++)
        #pragma unroll
        for (int r = 0; r < 4; r++) acc[ct][r] = 0.f;

    for (int t = 0; t < 2048; t++){
        // prefetch this step's xW partials (HBM, hidden under the poll)
        const float* xwp = xW + ((size_t)t * 32 + b) * 2048 + col;
        float zx0 = xwp[0], zx1 = xwp[512], zx2 = xwp[1024], zx3 = xwp[1536];

        // ---- wait for h_t: poll 32 producer flags of this bt (L2 RT) ----
        if (t > 0){
            const unsigned* fp = done + bt * 32 + (lane & 31);
            const unsigned tgt = (unsigned)t;
            while (true){
                unsigned f;
                asm volatile("global_load_dword %0, %1, off sc0\n\ts_waitcnt vmcnt(0)"
                             : "=v"(f) : "v"(fp) : "memory");
                if (__all(f >= tgt)) break;
                __builtin_amdgcn_s_sleep(1);
            }
        }

        // ---- payload: 8 x dwordx4 sc0, frag-packed, fully coalesced ----
        const unsigned* hb = hbuf + ((size_t)(t & 1) * 2 + bt) * 8192;
        const unsigned* p0 = hb + (size_t)(kq * 4 + 0) * 512 + (size_t)lane * 8;
        const unsigned* p1 = hb + (size_t)(kq * 4 + 2) * 512 + (size_t)lane * 8;
        uint4 dd[8];
        asm volatile(
            "global_load_dwordx4 %0, %8, off sc0\n\t"
            "global_load_dwordx4 %1, %8, off offset:16 sc0\n\t"
            "global_load_dwordx4 %2, %8, off offset:2048 sc0\n\t"
            "global_load_dwordx4 %3, %8, off offset:2064 sc0\n\t"
            "global_load_dwordx4 %4, %9, off sc0\n\t"
            "global_load_dwordx4 %5, %9, off offset:16 sc0\n\t"
            "global_load_dwordx4 %6, %9, off offset:2048 sc0\n\t"
            "global_load_dwordx4 %7, %9, off offset:2064 sc0\n\t"
            "s_waitcnt vmcnt(0)"
            : "=&v"(dd[0]), "=&v"(dd[1]), "=&v"(dd[2]), "=&v"(dd[3]),
              "=&v"(dd[4]), "=&v"(dd[5]), "=&v"(dd[6]), "=&v"(dd[7])
            : "v"(p0), "v"(p1) : "memory");

        // ---- h_t @ U (3-pass hi/lo) ----
        #pragma unroll
        for (int i = 0; i < 4; i++){
            bf16x8 ah, al;
            #pragma unroll
            for (int h = 0; h < 2; h++){
                uint4 q = dd[i * 2 + h];
                unsigned u0 = q.x, u1 = q.y, u2 = q.z, u3 = q.w;
                ah[h * 4 + 0] = (short)(u0 & 0xffffu); al[h * 4 + 0] = (short)(u0 >> 16);
                ah[h * 4 + 1] = (short)(u1 & 0xffffu); al[h * 4 + 1] = (short)(u1 >> 16);
                ah[h * 4 + 2] = (short)(u2 & 0xffffu); al[h * 4 + 2] = (short)(u2 >> 16);
                ah[h * 4 + 3] = (short)(u3 & 0xffffu); al[h * 4 + 3] = (short)(u3 >> 16);
            }
            #pragma unroll
            for (int ct = 0; ct < 4; ct++){
                acc[ct] = __builtin_amdgcn_mfma_f32_16x16x32_bf16(ah, uh[i][ct], acc[ct], 0, 0, 0);
                acc[ct] = __builtin_amdgcn_mfma_f32_16x16x32_bf16(ah, ul[i][ct], acc[ct], 0, 0, 0);
                acc[ct] = __builtin_amdgcn_mfma_f32_16x16x32_bf16(al, uh[i][ct], acc[ct], 0, 0, 0);
            }
        }

        // ---- reduce partial z across the 4 K-quarter waves ----
        #pragma unroll
        for (int ct = 0; ct < 4; ct++)
            #pragma unroll
            for (int r = 0; r < 4; r++)
                z_lds[kq][kgrp * 4 + r][ct * 16 + lc] = acc[ct][r];
        __syncthreads();

        // ---- gates ----
        {
            float z0 = z_lds[0][cb][chc]      + z_lds[1][cb][chc]      + z_lds[2][cb][chc]      + z_lds[3][cb][chc]      + zx0 + bias_g[0];
            float z1 = z_lds[0][cb][16 + chc] + z_lds[1][cb][16 + chc] + z_lds[2][cb][16 + chc] + z_lds[3][cb][16 + chc] + zx1 + bias_g[1];
            float z2 = z_lds[0][cb][32 + chc] + z_lds[1][cb][32 + chc] + z_lds[2][cb][32 + chc] + z_lds[3][cb][32 + chc] + zx2 + bias_g[2];
            float z3 = z_lds[0][cb][48 + chc] + z_lds[1][cb][48 + chc] + z_lds[2][cb][48 + chc] + z_lds[3][cb][48 + chc] + zx3 + bias_g[3];
            float ig = 1.f / (1.f + __expf(-z0));
            float fg = 1.f / (1.f + __expf(-z1));
            float gg = tanhf(z2);
            float og = 1.f / (1.f + __expf(-z3));
            float cn = fg * c_state + ig * gg;
            c_state = cn;
            float hn = og * tanhf(cn);

            out[16384 + ((size_t)t * 32 + b) * 512 + col] = hn;
            if (t == 2047){
                out[(size_t)b * 512 + col] = hn;
                out[16384 + (size_t)2048 * 32 * 512 + (size_t)b * 512 + col] = hn;
            }
            unsigned short hi = f2bf(hn);
            unsigned short lo = f2bf(hn - bf2f(hi));
            unsigned pv = (unsigned)hi | ((unsigned)lo << 16);
            st_sc0(((t + 1) & 1) ? hw1 : hw0, pv);
        }

        // drain stores, then release this WG's flag
        asm volatile("s_waitcnt vmcnt(0)" ::: "memory");
        __syncthreads();
        if (tid == 0) st_sc0(&done[bt * 32 + cg], (unsigned)(t + 1));

        #pragma unroll
        for (int ct = 0; ct < 4; ct++)
            #pragma unroll
            for (int r = 0; r < 4; r++) acc[ct][r] = 0.f;
    }
}

// ============================ FALLBACK (R4, verbatim) ======================
__global__ void prep_r4(const float* __restrict__ W, const float* __restrict__ U,
                        const float* __restrict__ h0,
                        unsigned short* __restrict__ Wh, unsigned short* __restrict__ Wl,
                        unsigned short* __restrict__ Uh, unsigned short* __restrict__ Ul,
                        u64t* __restrict__ hpkT){
    int idx = blockIdx.x * blockDim.x + threadIdx.x;
    int stride = gridDim.x * blockDim.x;
    const int total = 2 * 512 * 2048;
    for (int i = idx; i < total; i += stride){
        int mat = i >> 20;
        int r = i & 1048575;
        int k = r >> 11;
        int col = r & 2047;
        float v = (mat ? U : W)[(size_t)k * 2048 + col];
        unsigned short hi = f2bf(v);
        unsigned short lo = f2bf(v - bf2f(hi));
        int wg = (col & 511) >> 4;
        int hc = col & 15;
        int g  = col >> 9;
        int kb = k >> 5;
        int kgrp = (k >> 3) & 3;
        int j = k & 7;
        size_t dst = (size_t)wg * 32768 + (size_t)kb * 2048 + (size_t)g * 512
                   + (size_t)(kgrp * 16 + hc) * 8 + j;
        if (mat){ Uh[dst] = hi; Ul[dst] = lo; } else { Wh[dst] = hi; Wl[dst] = lo; }
    }
    for (int i = idx; i < 32 * 512; i += stride){
        int b = i >> 9;
        int k = i & 511;
        float v = h0[i];
        unsigned short hi = f2bf(v);
        unsigned short lo = f2bf(v - bf2f(hi));
        hpkT[(size_t)k * 32 + b] = (u64t)((unsigned)hi | ((unsigned)lo << 16));
        hpkT[16384 + (size_t)k * 32 + b] = 0x8000000000000000ULL;
    }
}

__global__ __launch_bounds__(512, 2) void lstm_scan_r4(
        const float* __restrict__ src, const float* __restrict__ bias,
        const float* __restrict__ c0,
        const unsigned short* __restrict__ Wh, const unsigned short* __restrict__ Wl,
        const unsigned short* __restrict__ Uh, const unsigned short* __restrict__ Ul,
        u64t* __restrict__ hpkT,
        float* __restrict__ out){
    const int tid  = threadIdx.x;
    const int wg   = blockIdx.x;
    const int lane = tid & 63;
    const int w    = tid >> 6;
    const int bt   = w >> 2;
    const int kq   = w & 3;
    const int lc   = lane & 15;
    const int kgrp = lane >> 4;
    const int row  = bt * 16 + lc;

    __shared__ unsigned int hlds[8][128][17];
    __shared__ float z_lds[4][32][65];

    const int cb  = tid >> 4;
    const int chc = tid & 15;
    const int col = wg * 16 + chc;
    float c_state = c0[(size_t)cb * 512 + col];
    float bias_g[4];
    #pragma unroll
    for (int g = 0; g < 4; g++) bias_g[g] = bias[g * 512 + col];

    const uint4* WhF = reinterpret_cast<const uint4*>(Wh) + (size_t)wg * 4096;
    const uint4* WlF = reinterpret_cast<const uint4*>(Wl) + (size_t)wg * 4096;
    const uint4* UhF = reinterpret_cast<const uint4*>(Uh) + (size_t)wg * 4096;
    const uint4* UlF = reinterpret_cast<const uint4*>(Ul) + (size_t)wg * 4096;

    f32x4 acc[4];
    #pragma unroll
    for (int ct = 0; ct < 4; ct++)
        #pragma unroll
        for (int r = 0; r < 4; r++) acc[ct][r] = 0.f;

    auto phaseA = [&](int t){
        #pragma unroll
        for (int i = 0; i < 4; i++){
            int kb = kq * 4 + i;
            const float* xp = src + ((size_t)row * 2048 + t) * 512 + kb * 32 + kgrp * 8;
            float xv[8];
            *reinterpret_cast<float4*>(&xv[0]) = *reinterpret_cast<const float4*>(xp);
            *reinterpret_cast<float4*>(&xv[4]) = *reinterpret_cast<const float4*>(xp + 4);
            bf16x8 ah, al;
            #pragma unroll
            for (int j = 0; j < 8; j++){
                unsigned short hi = f2bf(xv[j]);
                ah[j] = (short)hi;
                al[j] = (short)f2bf(xv[j] - bf2f(hi));
            }
            #pragma unroll
            for (int ct = 0; ct < 4; ct++){
                uint4 bh4 = WhF[kb * 256 + ct * 64 + lane];
                uint4 bl4 = WlF[kb * 256 + ct * 64 + lane];
                bf16x8 bh = *reinterpret_cast<bf16x8*>(&bh4);
                bf16x8 bl = *reinterpret_cast<bf16x8*>(&bl4);
                acc[ct] = __builtin_amdgcn_mfma_f32_16x16x32_bf16(ah, bh, acc[ct], 0, 0, 0);
                acc[ct] = __builtin_amdgcn_mfma_f32_16x16x32_bf16(ah, bl, acc[ct], 0, 0, 0);
                acc[ct] = __builtin_amdgcn_mfma_f32_16x16x32_bf16(al, bh, acc[ct], 0, 0, 0);
            }
        }
    };

    phaseA(0);

    for (int t = 0; t < 2048; t++){
        const u64t* hp = hpkT + (size_t)(t & 1) * 16384 + (size_t)(kq * 128) * 32 + bt * 16;
        u64t hv[32];
        {
            const unsigned tag = (unsigned)t;
            while (true){
                #pragma unroll
                for (int m = 0; m < 32; m++){
                    int c = m * 64 + lane;
                    hv[m] = __hip_atomic_load(hp + (size_t)(c >> 4) * 32 + (c & 15),
                                              __ATOMIC_RELAXED, __HIP_MEMORY_SCOPE_AGENT);
                }
                bool ok = true;
                #pragma unroll
                for (int m = 0; m < 32; m++)
                    ok = ok && ((unsigned)(hv[m] >> 32) == tag);
                if (__all(ok)) break;
                __builtin_amdgcn_s_sleep(2);
            }
        }
        #pragma unroll
        for (int m = 0; m < 32; m++){
            int c = m * 64 + lane;
            hlds[w][c >> 4][c & 15] = (unsigned)hv[m];
        }
        __syncthreads();

        #pragma unroll
        for (int i = 0; i < 4; i++){
            int kb = kq * 4 + i;
            bf16x8 ah, al;
            #pragma unroll
            for (int j = 0; j < 8; j++){
                unsigned p = hlds[w][i * 32 + kgrp * 8 + j][lc];
                ah[j] = (short)(p & 0xffffu);
                al[j] = (short)(p >> 16);
            }
            #pragma unroll
            for (int ct = 0; ct < 4; ct++){
                uint4 uh4 = UhF[kb * 256 + ct * 64 + lane];
                uint4 ul4 = UlF[kb * 256 + ct * 64 + lane];
                bf16x8 uh = *reinterpret_cast<bf16x8*>(&uh4);
                bf16x8 ulf = *reinterpret_cast<bf16x8*>(&ul4);
                acc[ct] = __builtin_amdgcn_mfma_f32_16x16x32_bf16(ah, uh, acc[ct], 0, 0, 0);
                acc[ct] = __builtin_amdgcn_mfma_f32_16x16x32_bf16(ah, ulf, acc[ct], 0, 0, 0);
                acc[ct] = __builtin_amdgcn_mfma_f32_16x16x32_bf16(al, uh, acc[ct], 0, 0, 0);
            }
        }

        #pragma unroll
        for (int ct = 0; ct < 4; ct++)
            #pragma unroll
            for (int r = 0; r < 4; r++)
                z_lds[kq][bt * 16 + kgrp * 4 + r][ct * 16 + lc] = acc[ct][r];
        __syncthreads();

        {
            float z[4];
            #pragma unroll
            for (int g = 0; g < 4; g++)
                z[g] = z_lds[0][cb][g * 16 + chc] + z_lds[1][cb][g * 16 + chc]
                     + z_lds[2][cb][g * 16 + chc] + z_lds[3][cb][g * 16 + chc] + bias_g[g];
            float ig = 1.f / (1.f + __expf(-z[0]));
            float fg = 1.f / (1.f + __expf(-z[1]));
            float gg = tanhf(z[2]);
            float og = 1.f / (1.f + __expf(-z[3]));
            float cn = fg * c_state + ig * gg;
            c_state = cn;
            float hn = og * tanhf(cn);
            out[16384 + ((size_t)t * 32 + cb) * 512 + col] = hn;
            if (t == 2047){
                out[(size_t)cb * 512 + col] = hn;
                out[16384 + (size_t)2048 * 32 * 512 + (size_t)cb * 512 + col] = hn;
            }
            unsigned short hi = f2bf(hn);
            unsigned short lo = f2bf(hn - bf2f(hi));
            u64t pv = ((u64t)(unsigned)(t + 1) << 32)
                    | (u64t)((unsigned)hi | ((unsigned)lo << 16));
            __hip_atomic_store(&hpkT[(size_t)((t + 1) & 1) * 16384 + (size_t)col * 32 + cb],
                               pv, __ATOMIC_RELAXED, __HIP_MEMORY_SCOPE_AGENT);
        }

        #pragma unroll
        for (int ct = 0; ct < 4; ct++)
            #pragma unroll
            for (int r = 0; r < 4; r++) acc[ct][r] = 0.f;
        if (t + 1 < 2048) phaseA(t + 1);
    }
}

// ============================ LAUNCH =======================================
extern "C" void kernel_launch(void* const* d_in, const int* in_sizes, int n_in,
                              void* d_out, int out_size, void* d_ws, size_t ws_size,
                              hipStream_t stream){
    const float* src = (const float*)d_in[0];
    const float* W   = (const float*)d_in[1];
    const float* U   = (const float*)d_in[2];
    const float* b   = (const float*)d_in[3];
    const float* h0  = (const float*)d_in[4];
    const float* c0  = (const float*)d_in[5];
    float* out = (float*)d_out;
    char* ws = (char*)d_ws;

    if (ws_size >= NEED_WS){
        float*          xW   = (float*)(ws);
        unsigned short* Wh   = (unsigned short*)(ws + 0x20000000ull);
        unsigned short* Wl   = (unsigned short*)(ws + 0x20200000ull);
        unsigned short* Uh   = (unsigned short*)(ws + 0x20400000ull);
        unsigned short* Ul   = (unsigned short*)(ws + 0x20600000ull);
        unsigned*       hbuf = (unsigned*)(ws + 0x20800000ull);
        unsigned*       done = (unsigned*)(ws + 0x20820000ull);
        unsigned*       ecnt = (unsigned*)(ws + 0x20821000ull);
        unsigned*       elec = (unsigned*)(ws + 0x20821020ull);

        hipMemsetAsync(done, 0, 256, stream);
        hipMemsetAsync(ecnt, 0, 32, stream);
        hipMemsetAsync(elec, 0xFF, 4, stream);
        prep_new<<<1024, 256, 0, stream>>>(W, U, h0, Wh, Wl, Uh, Ul, hbuf);
        xw_gemm<<<16384, 256, 0, stream>>>(src, Wh, Wl, xW);
        lstm_scan_xcd<<<512, 256, 0, stream>>>(b, c0, Uh, Ul, hbuf, done, ecnt, elec, xW, out);
    } else {
        u64t*           hpkT = (u64t*)(ws);
        unsigned short* Wh   = (unsigned short*)(ws + 262144);
        unsigned short* Wl   = Wh + 1048576;
        unsigned short* Uh   = Wl + 1048576;
        unsigned short* Ul   = Uh + 1048576;
        prep_r4<<<1024, 256, 0, stream>>>(W, U, h0, Wh, Wl, Uh, Ul, hpkT);
        lstm_scan_r4<<<32, 512, 0, stream>>>(src, b, c0, Wh, Wl, Uh, Ul, hpkT, out);
    }
}

// Round 7
// 20138.287 us; speedup vs baseline: 1.2373x; 1.2373x over previous
//
#include <hip/hip_runtime.h>
#include <stdint.h>

#define T_STEPS 2048
#define BATCH 32
#define EDIM 512
#define HDIM 512
#define NWG 32
#define NTHR 512

typedef __attribute__((ext_vector_type(8))) short bf16x8;
typedef __attribute__((ext_vector_type(4))) float f32x4;
typedef unsigned long long u64t;

// ws layout (bytes):
//   [0, 0x20000)     hbuf[2][32][512] u32 packed h (bf16hi | bf16lo<<16), [b][k]
//   [0x20000, +8)    cnt[2] u32 arrival counters (memset 0 per launch)
//   [0x21000, +2MB)  Wh frags [cg32][kb16][ct4][lane64][8] shorts
//   then Wl, Uh, Ul (2MB each).  total ~8.13MB

__device__ inline unsigned short f2bf(float x){
    unsigned u = __float_as_uint(x);
    unsigned r = (u + 0x7fffu + ((u >> 16) & 1u)) >> 16;
    return (unsigned short)r;
}
__device__ inline float bf2f(unsigned short s){
    return __uint_as_float(((unsigned)s) << 16);
}

__global__ void prep_kernel(const float* __restrict__ W, const float* __restrict__ U,
                            const float* __restrict__ h0,
                            unsigned short* __restrict__ Wh, unsigned short* __restrict__ Wl,
                            unsigned short* __restrict__ Uh, unsigned short* __restrict__ Ul,
                            unsigned* __restrict__ hbuf){
    int idx = blockIdx.x * blockDim.x + threadIdx.x;
    int stride = gridDim.x * blockDim.x;
    const int total = 2 * EDIM * 2048;  // 2^21
    for (int i = idx; i < total; i += stride){
        int mat = i >> 20;             // 0=W, 1=U
        int r = i & 1048575;
        int k = r >> 11;               // row in [0,512)
        int col = r & 2047;            // gate column in [0,2048)
        float v = (mat ? U : W)[(size_t)k * 2048 + col];
        unsigned short hi = f2bf(v);
        unsigned short lo = f2bf(v - bf2f(hi));
        int cg = (col & 511) >> 4;     // h-col block (16 cols per wg)
        int hc = col & 15;
        int g  = col >> 9;             // gate 0..3 == MFMA col-tile
        int kb = k >> 5;
        int kgrp = (k >> 3) & 3;
        int j = k & 7;
        size_t dst = (size_t)cg * 32768 + (size_t)kb * 2048 + (size_t)g * 512
                   + (size_t)(kgrp * 16 + hc) * 8 + j;
        if (mat){ Uh[dst] = hi; Ul[dst] = lo; } else { Wh[dst] = hi; Wl[dst] = lo; }
    }
    // h0 -> hbuf parity0, natural [b][k] packed layout
    for (int i = idx; i < BATCH * HDIM; i += stride){
        float v = h0[i];
        unsigned short hi = f2bf(v);
        unsigned short lo = f2bf(v - bf2f(hi));
        hbuf[i] = (unsigned)hi | ((unsigned)lo << 16);
    }
}

__global__ __launch_bounds__(NTHR, 2) void lstm_scan(
        const float* __restrict__ src, const float* __restrict__ bias,
        const float* __restrict__ c0,
        const unsigned short* __restrict__ Wh, const unsigned short* __restrict__ Wl,
        const unsigned short* __restrict__ Uh, const unsigned short* __restrict__ Ul,
        unsigned* __restrict__ hbuf, unsigned* __restrict__ cnt,
        float* __restrict__ out){
    const int tid  = threadIdx.x;
    const int cg   = blockIdx.x;        // 0..31 -> h-cols [cg*16, cg*16+16)
    const int lane = tid & 63;
    const int w    = tid >> 6;          // wave 0..7
    const int bt   = w >> 2;            // batch tile (rows bt*16..)
    const int kq   = w & 3;             // K quarter (128 k-values)
    const int lc   = lane & 15;
    const int kgrp = lane >> 4;
    const int row  = bt * 16 + lc;      // batch index for A frags

    __shared__ float z_lds[4][BATCH][65];   // [kq][b][ct*16+hc], padded

    // gate cell: one per thread
    const int cb  = tid >> 4;      // batch 0..31
    const int chc = tid & 15;      // h-col within cg
    const int col = cg * 16 + chc;
    float c_state = c0[(size_t)cb * HDIM + col];
    float bias_g[4];
    #pragma unroll
    for (int g = 0; g < 4; g++) bias_g[g] = bias[g * HDIM + col];

    const uint4* WhF = reinterpret_cast<const uint4*>(Wh) + (size_t)cg * 4096;
    const uint4* WlF = reinterpret_cast<const uint4*>(Wl) + (size_t)cg * 4096;
    const uint4* UhF = reinterpret_cast<const uint4*>(Uh) + (size_t)cg * 4096;
    const uint4* UlF = reinterpret_cast<const uint4*>(Ul) + (size_t)cg * 4096;

    f32x4 acc[4];
    #pragma unroll
    for (int ct = 0; ct < 4; ct++)
        #pragma unroll
        for (int r = 0; r < 4; r++) acc[ct][r] = 0.f;

    // phase A: x_t @ W for this wave's (bt, kq), all 4 gate col-tiles
    auto phaseA = [&](int t){
        #pragma unroll
        for (int i = 0; i < 4; i++){
            int kb = kq * 4 + i;
            const float* xp = src + ((size_t)row * T_STEPS + t) * EDIM + kb * 32 + kgrp * 8;
            float xv[8];
            *reinterpret_cast<float4*>(&xv[0]) = *reinterpret_cast<const float4*>(xp);
            *reinterpret_cast<float4*>(&xv[4]) = *reinterpret_cast<const float4*>(xp + 4);
            bf16x8 ah, al;
            #pragma unroll
            for (int j = 0; j < 8; j++){
                unsigned short hi = f2bf(xv[j]);
                ah[j] = (short)hi;
                al[j] = (short)f2bf(xv[j] - bf2f(hi));
            }
            #pragma unroll
            for (int ct = 0; ct < 4; ct++){
                uint4 bh4 = WhF[kb * 256 + ct * 64 + lane];
                uint4 bl4 = WlF[kb * 256 + ct * 64 + lane];
                bf16x8 bh = *reinterpret_cast<bf16x8*>(&bh4);
                bf16x8 bl = *reinterpret_cast<bf16x8*>(&bl4);
                acc[ct] = __builtin_amdgcn_mfma_f32_16x16x32_bf16(ah, bh, acc[ct], 0, 0, 0);
                acc[ct] = __builtin_amdgcn_mfma_f32_16x16x32_bf16(ah, bl, acc[ct], 0, 0, 0);
                acc[ct] = __builtin_amdgcn_mfma_f32_16x16x32_bf16(al, bh, acc[ct], 0, 0, 0);
            }
        }
    };

    phaseA(0);

    for (int t = 0; t < T_STEPS; t++){
        // ---- wait for h_t: single-counter broadcast poll (wave 0 only) ----
        if (t > 0){
            if (w == 0){
                const unsigned need = 32u * (unsigned)((t + 1) >> 1);
                while (__hip_atomic_load(&cnt[t & 1], __ATOMIC_RELAXED, __HIP_MEMORY_SCOPE_AGENT) < need)
                    __builtin_amdgcn_s_sleep(1);
            }
            __syncthreads();
        }

        // ---- payload: 16 dense u64 agent loads -> A fragments directly ----
        const u64t* hp = reinterpret_cast<const u64t*>(hbuf)
                       + (size_t)(t & 1) * 8192 + (size_t)row * 256;
        u64t hv[16];
        #pragma unroll
        for (int i = 0; i < 4; i++){
            int base = (kq * 4 + i) * 16 + kgrp * 4;   // u64 units within the row
            #pragma unroll
            for (int jp = 0; jp < 4; jp++)
                hv[i * 4 + jp] = __hip_atomic_load(hp + base + jp,
                                                   __ATOMIC_RELAXED, __HIP_MEMORY_SCOPE_AGENT);
        }

        // ---- h_t @ U into acc (3-pass hi/lo) ----
        #pragma unroll
        for (int i = 0; i < 4; i++){
            int kb = kq * 4 + i;
            bf16x8 ah, al;
            #pragma unroll
            for (int jp = 0; jp < 4; jp++){
                u64t q = hv[i * 4 + jp];
                unsigned a = (unsigned)q;
                unsigned b = (unsigned)(q >> 32);
                ah[jp * 2    ] = (short)(a & 0xffffu); al[jp * 2    ] = (short)(a >> 16);
                ah[jp * 2 + 1] = (short)(b & 0xffffu); al[jp * 2 + 1] = (short)(b >> 16);
            }
            #pragma unroll
            for (int ct = 0; ct < 4; ct++){
                uint4 uh4 = UhF[kb * 256 + ct * 64 + lane];
                uint4 ul4 = UlF[kb * 256 + ct * 64 + lane];
                bf16x8 uh = *reinterpret_cast<bf16x8*>(&uh4);
                bf16x8 ul = *reinterpret_cast<bf16x8*>(&ul4);
                acc[ct] = __builtin_amdgcn_mfma_f32_16x16x32_bf16(ah, uh, acc[ct], 0, 0, 0);
                acc[ct] = __builtin_amdgcn_mfma_f32_16x16x32_bf16(ah, ul, acc[ct], 0, 0, 0);
                acc[ct] = __builtin_amdgcn_mfma_f32_16x16x32_bf16(al, uh, acc[ct], 0, 0, 0);
            }
        }

        // ---- exchange partial z through LDS ----
        #pragma unroll
        for (int ct = 0; ct < 4; ct++)
            #pragma unroll
            for (int r = 0; r < 4; r++)
                z_lds[kq][bt * 16 + kgrp * 4 + r][ct * 16 + lc] = acc[ct][r];
        __syncthreads();

        // ---- gates: all 512 threads, one cell (cb, chc) each ----
        {
            float z[4];
            #pragma unroll
            for (int g = 0; g < 4; g++)
                z[g] = z_lds[0][cb][g * 16 + chc] + z_lds[1][cb][g * 16 + chc]
                     + z_lds[2][cb][g * 16 + chc] + z_lds[3][cb][g * 16 + chc] + bias_g[g];
            float ig = 1.f / (1.f + __expf(-z[0]));
            float fg = 1.f / (1.f + __expf(-z[1]));
            float gg = tanhf(z[2]);
            float og = 1.f / (1.f + __expf(-z[3]));
            float cn = fg * c_state + ig * gg;
            c_state = cn;
            float hn = og * tanhf(cn);
            out[16384 + ((size_t)t * BATCH + cb) * HDIM + col] = hn;   // hs[t][b][col]
            if (t == T_STEPS - 1){
                out[(size_t)cb * HDIM + col] = hn;                                          // h_T (out 0)
                out[16384 + (size_t)T_STEPS * BATCH * HDIM + (size_t)cb * HDIM + col] = hn; // h_T (out 2)
            }
            unsigned short hi = f2bf(hn);
            unsigned short lo = f2bf(hn - bf2f(hi));
            __hip_atomic_store(&hbuf[(size_t)((t + 1) & 1) * (BATCH * HDIM) + (size_t)cb * HDIM + col],
                               (unsigned)hi | ((unsigned)lo << 16),
                               __ATOMIC_RELAXED, __HIP_MEMORY_SCOPE_AGENT);
        }
        // barrier drains every wave's vmcnt -> all payload stores at coherence
        // point before tid0's release add
        __syncthreads();
        if (tid == 0)
            __hip_atomic_fetch_add(&cnt[(t + 1) & 1], 1u,
                                   __ATOMIC_RELAXED, __HIP_MEMORY_SCOPE_AGENT);

        // ---- phase A for t+1 (overlaps other WGs' progress) ----
        #pragma unroll
        for (int ct = 0; ct < 4; ct++)
            #pragma unroll
            for (int r = 0; r < 4; r++) acc[ct][r] = 0.f;
        if (t + 1 < T_STEPS) phaseA(t + 1);
    }
}

extern "C" void kernel_launch(void* const* d_in, const int* in_sizes, int n_in,
                              void* d_out, int out_size, void* d_ws, size_t ws_size,
                              hipStream_t stream){
    const float* src = (const float*)d_in[0];
    const float* W   = (const float*)d_in[1];
    const float* U   = (const float*)d_in[2];
    const float* b   = (const float*)d_in[3];
    const float* h0  = (const float*)d_in[4];
    const float* c0  = (const float*)d_in[5];
    float* out = (float*)d_out;

    char* ws = (char*)d_ws;
    unsigned*       hbuf = (unsigned*)(ws);
    unsigned*       cnt  = (unsigned*)(ws + 0x20000);
    unsigned short* Wh   = (unsigned short*)(ws + 0x21000);
    unsigned short* Wl   = Wh + 1048576;
    unsigned short* Uh   = Wl + 1048576;
    unsigned short* Ul   = Uh + 1048576;

    hipMemsetAsync(cnt, 0, 8, stream);
    prep_kernel<<<1024, 256, 0, stream>>>(W, U, h0, Wh, Wl, Uh, Ul, hbuf);
    lstm_scan<<<NWG, NTHR, 0, stream>>>(src, b, c0, Wh, Wl, Uh, Ul, hbuf, cnt, out);
}

// Round 8
// 12101.987 us; speedup vs baseline: 2.0589x; 1.6640x over previous
//
#include <hip/hip_runtime.h>
#include <stdint.h>

#define T_STEPS 2048
#define BATCH 32
#define EDIM 512
#define HDIM 512

typedef __attribute__((ext_vector_type(8))) short bf16x8;
typedef __attribute__((ext_vector_type(4))) float f32x4;
typedef unsigned long long u64t;

// ---- new-path ws layout ----
//   0x000000 hbuf[2][32][512] u32 packed h      (128KB)
//   0x020000 cnt[2] u32 (pad 4KB)
//   0x021000 c_ws[32][512] f32                  (64KB)
//   0x031000 Wh 2MB | 0x231000 Wl | 0x431000 Uh | 0x631000 Ul
//   0x831000 xWc[TCH][32][2048] f32             (TCH * 256KB)
#define FIXED_WS 0x831000ull

__device__ inline unsigned short f2bf(float x){
    unsigned u = __float_as_uint(x);
    unsigned r = (u + 0x7fffu + ((u >> 16) & 1u)) >> 16;
    return (unsigned short)r;
}
__device__ inline float bf2f(unsigned short s){
    return __uint_as_float(((unsigned)s) << 16);
}

// Shared prep: frag-pack W/U (hi/lo) + init hbuf parity0 with h0. (proven R7)
__global__ void prep_kernel(const float* __restrict__ W, const float* __restrict__ U,
                            const float* __restrict__ h0,
                            unsigned short* __restrict__ Wh, unsigned short* __restrict__ Wl,
                            unsigned short* __restrict__ Uh, unsigned short* __restrict__ Ul,
                            unsigned* __restrict__ hbuf){
    int idx = blockIdx.x * blockDim.x + threadIdx.x;
    int stride = gridDim.x * blockDim.x;
    const int total = 2 * EDIM * 2048;
    for (int i = idx; i < total; i += stride){
        int mat = i >> 20;
        int r = i & 1048575;
        int k = r >> 11;
        int col = r & 2047;
        float v = (mat ? U : W)[(size_t)k * 2048 + col];
        unsigned short hi = f2bf(v);
        unsigned short lo = f2bf(v - bf2f(hi));
        int cg = (col & 511) >> 4;
        int hc = col & 15;
        int g  = col >> 9;
        int kb = k >> 5;
        int kgrp = (k >> 3) & 3;
        int j = k & 7;
        size_t dst = (size_t)cg * 32768 + (size_t)kb * 2048 + (size_t)g * 512
                   + (size_t)(kgrp * 16 + hc) * 8 + j;
        if (mat){ Uh[dst] = hi; Ul[dst] = lo; } else { Wh[dst] = hi; Wl[dst] = lo; }
    }
    for (int i = idx; i < BATCH * HDIM; i += stride){
        float v = h0[i];
        unsigned short hi = f2bf(v);
        unsigned short lo = f2bf(v - bf2f(hi));
        hbuf[i] = (unsigned)hi | ((unsigned)lo << 16);
    }
}

// xWc[tc] = src[:, t0+tc, :] @ W   (plain GEMM, full chip, 3-pass hi/lo)
__global__ __launch_bounds__(256) void xw_gemm_chunk(
        const float* __restrict__ src,
        const unsigned short* __restrict__ Wh, const unsigned short* __restrict__ Wl,
        float* __restrict__ xWc, int t0){
    const int bid = blockIdx.x;          // (TCH/4) * 32
    const int mtile = bid >> 5;
    const int cg = bid & 31;
    const int tid = threadIdx.x;
    const int lane = tid & 63;
    const int w = tid >> 6;
    const int tc = mtile * 4 + w;
    const int t = t0 + tc;
    const int lc = lane & 15;
    const int kgrp = lane >> 4;

    const uint4* WhF = reinterpret_cast<const uint4*>(Wh) + (size_t)cg * 4096;
    const uint4* WlF = reinterpret_cast<const uint4*>(Wl) + (size_t)cg * 4096;

    f32x4 acc[2][4];
    #pragma unroll
    for (int bt = 0; bt < 2; bt++)
        #pragma unroll
        for (int ct = 0; ct < 4; ct++)
            #pragma unroll
            for (int r = 0; r < 4; r++) acc[bt][ct][r] = 0.f;

    for (int kb = 0; kb < 16; kb++){
        bf16x8 ah[2], al[2];
        #pragma unroll
        for (int bt = 0; bt < 2; bt++){
            const float* xp = src + ((size_t)(bt * 16 + lc) * 2048 + t) * 512 + kb * 32 + kgrp * 8;
            float xv[8];
            *reinterpret_cast<float4*>(&xv[0]) = *reinterpret_cast<const float4*>(xp);
            *reinterpret_cast<float4*>(&xv[4]) = *reinterpret_cast<const float4*>(xp + 4);
            #pragma unroll
            for (int j = 0; j < 8; j++){
                unsigned short hi = f2bf(xv[j]);
                ah[bt][j] = (short)hi;
                al[bt][j] = (short)f2bf(xv[j] - bf2f(hi));
            }
        }
        #pragma unroll
        for (int ct = 0; ct < 4; ct++){
            uint4 bh4 = WhF[kb * 256 + ct * 64 + lane];
            uint4 bl4 = WlF[kb * 256 + ct * 64 + lane];
            bf16x8 bh = *reinterpret_cast<bf16x8*>(&bh4);
            bf16x8 bl = *reinterpret_cast<bf16x8*>(&bl4);
            #pragma unroll
            for (int bt = 0; bt < 2; bt++){
                acc[bt][ct] = __builtin_amdgcn_mfma_f32_16x16x32_bf16(ah[bt], bh, acc[bt][ct], 0, 0, 0);
                acc[bt][ct] = __builtin_amdgcn_mfma_f32_16x16x32_bf16(ah[bt], bl, acc[bt][ct], 0, 0, 0);
                acc[bt][ct] = __builtin_amdgcn_mfma_f32_16x16x32_bf16(al[bt], bh, acc[bt][ct], 0, 0, 0);
            }
        }
    }
    #pragma unroll
    for (int bt = 0; bt < 2; bt++)
        #pragma unroll
        for (int ct = 0; ct < 4; ct++)
            #pragma unroll
            for (int r = 0; r < 4; r++){
                int row_b = bt * 16 + kgrp * 4 + r;
                xWc[((size_t)tc * 32 + row_b) * 2048 + ct * 512 + cg * 16 + lc] = acc[bt][ct][r];
            }
}

// Scan with empty loop body: no src, no f2bf, U register-resident.
// Sync protocol identical to R7 (proven): counter release + dense payload.
__global__ __launch_bounds__(512, 1) void lstm_scan_fast(
        const float* __restrict__ bias, const float* __restrict__ c0,
        const unsigned short* __restrict__ Uh, const unsigned short* __restrict__ Ul,
        unsigned* __restrict__ hbuf, unsigned* __restrict__ cnt,
        const float* __restrict__ xWc, float* __restrict__ c_ws,
        float* __restrict__ out, int t0, int tlen){
    const int tid  = threadIdx.x;
    const int cg   = blockIdx.x;        // 0..31
    const int lane = tid & 63;
    const int w    = tid >> 6;
    const int bt   = w >> 2;
    const int kq   = w & 3;
    const int lc   = lane & 15;
    const int kgrp = lane >> 4;
    const int row  = bt * 16 + lc;

    __shared__ float z_lds[4][BATCH][65];

    const int cb  = tid >> 4;
    const int chc = tid & 15;
    const int col = cg * 16 + chc;
    float c_state = (t0 == 0) ? c0[(size_t)cb * HDIM + col] : c_ws[(size_t)cb * HDIM + col];
    float bias_g[4];
    #pragma unroll
    for (int g = 0; g < 4; g++) bias_g[g] = bias[g * HDIM + col];

    // U fragments -> registers (128 VGPR)
    const uint4* UhF = reinterpret_cast<const uint4*>(Uh) + (size_t)cg * 4096;
    const uint4* UlF = reinterpret_cast<const uint4*>(Ul) + (size_t)cg * 4096;
    bf16x8 ufh[4][4], ufl[4][4];
    #pragma unroll
    for (int i = 0; i < 4; i++){
        int kb = kq * 4 + i;
        #pragma unroll
        for (int ct = 0; ct < 4; ct++){
            uint4 a  = UhF[kb * 256 + ct * 64 + lane];
            uint4 b2 = UlF[kb * 256 + ct * 64 + lane];
            ufh[i][ct] = *reinterpret_cast<bf16x8*>(&a);
            ufl[i][ct] = *reinterpret_cast<bf16x8*>(&b2);
        }
    }

    f32x4 acc[4];
    #pragma unroll
    for (int ct = 0; ct < 4; ct++)
        #pragma unroll
        for (int r = 0; r < 4; r++) acc[ct][r] = 0.f;

    for (int t = t0; t < t0 + tlen; t++){
        // xW partials for this thread's cell — issued before the poll so the
        // L3 latency overlaps the wait.
        const float* xwp = xWc + ((size_t)(t - t0) * 32 + cb) * 2048 + col;
        float zx0 = xwp[0], zx1 = xwp[512], zx2 = xwp[1024], zx3 = xwp[1536];

        // ---- wait for h_t (single-counter broadcast poll, wave 0) ----
        if (t > 0){
            if (w == 0){
                const unsigned need = 32u * (unsigned)((t + 1) >> 1);
                while (__hip_atomic_load(&cnt[t & 1], __ATOMIC_RELAXED, __HIP_MEMORY_SCOPE_AGENT) < need)
                    __builtin_amdgcn_s_sleep(1);
            }
            __syncthreads();
        }

        // ---- payload: 16 dense u64 agent loads -> A fragments ----
        const u64t* hp = reinterpret_cast<const u64t*>(hbuf)
                       + (size_t)(t & 1) * 8192 + (size_t)row * 256;
        u64t hv[16];
        #pragma unroll
        for (int i = 0; i < 4; i++){
            int base = (kq * 4 + i) * 16 + kgrp * 4;
            #pragma unroll
            for (int jp = 0; jp < 4; jp++)
                hv[i * 4 + jp] = __hip_atomic_load(hp + base + jp,
                                                   __ATOMIC_RELAXED, __HIP_MEMORY_SCOPE_AGENT);
        }

        // ---- h_t @ U (3-pass hi/lo), U from registers ----
        #pragma unroll
        for (int i = 0; i < 4; i++){
            bf16x8 ah, al;
            #pragma unroll
            for (int jp = 0; jp < 4; jp++){
                u64t q = hv[i * 4 + jp];
                unsigned a = (unsigned)q;
                unsigned b = (unsigned)(q >> 32);
                ah[jp * 2    ] = (short)(a & 0xffffu); al[jp * 2    ] = (short)(a >> 16);
                ah[jp * 2 + 1] = (short)(b & 0xffffu); al[jp * 2 + 1] = (short)(b >> 16);
            }
            #pragma unroll
            for (int ct = 0; ct < 4; ct++){
                acc[ct] = __builtin_amdgcn_mfma_f32_16x16x32_bf16(ah, ufh[i][ct], acc[ct], 0, 0, 0);
                acc[ct] = __builtin_amdgcn_mfma_f32_16x16x32_bf16(ah, ufl[i][ct], acc[ct], 0, 0, 0);
                acc[ct] = __builtin_amdgcn_mfma_f32_16x16x32_bf16(al, ufh[i][ct], acc[ct], 0, 0, 0);
            }
        }

        // ---- exchange partial z through LDS ----
        #pragma unroll
        for (int ct = 0; ct < 4; ct++)
            #pragma unroll
            for (int r = 0; r < 4; r++)
                z_lds[kq][bt * 16 + kgrp * 4 + r][ct * 16 + lc] = acc[ct][r];
        __syncthreads();

        // ---- gates ----
        {
            float z0 = z_lds[0][cb][chc]      + z_lds[1][cb][chc]      + z_lds[2][cb][chc]      + z_lds[3][cb][chc]      + zx0 + bias_g[0];
            float z1 = z_lds[0][cb][16 + chc] + z_lds[1][cb][16 + chc] + z_lds[2][cb][16 + chc] + z_lds[3][cb][16 + chc] + zx1 + bias_g[1];
            float z2 = z_lds[0][cb][32 + chc] + z_lds[1][cb][32 + chc] + z_lds[2][cb][32 + chc] + z_lds[3][cb][32 + chc] + zx2 + bias_g[2];
            float z3 = z_lds[0][cb][48 + chc] + z_lds[1][cb][48 + chc] + z_lds[2][cb][48 + chc] + z_lds[3][cb][48 + chc] + zx3 + bias_g[3];
            float ig = 1.f / (1.f + __expf(-z0));
            float fg = 1.f / (1.f + __expf(-z1));
            float gg = tanhf(z2);
            float og = 1.f / (1.f + __expf(-z3));
            float cn = fg * c_state + ig * gg;
            c_state = cn;
            float hn = og * tanhf(cn);
            out[16384 + ((size_t)t * BATCH + cb) * HDIM + col] = hn;
            if (t == T_STEPS - 1){
                out[(size_t)cb * HDIM + col] = hn;
                out[16384 + (size_t)T_STEPS * BATCH * HDIM + (size_t)cb * HDIM + col] = hn;
            }
            unsigned short hi = f2bf(hn);
            unsigned short lo = f2bf(hn - bf2f(hi));
            __hip_atomic_store(&hbuf[(size_t)((t + 1) & 1) * (BATCH * HDIM) + (size_t)cb * HDIM + col],
                               (unsigned)hi | ((unsigned)lo << 16),
                               __ATOMIC_RELAXED, __HIP_MEMORY_SCOPE_AGENT);
        }
        __syncthreads();   // drain payload stores before the release add
        if (tid == 0)
            __hip_atomic_fetch_add(&cnt[(t + 1) & 1], 1u,
                                   __ATOMIC_RELAXED, __HIP_MEMORY_SCOPE_AGENT);

        #pragma unroll
        for (int ct = 0; ct < 4; ct++)
            #pragma unroll
            for (int r = 0; r < 4; r++) acc[ct][r] = 0.f;
    }
    c_ws[(size_t)cb * HDIM + col] = c_state;
}

// ============================ FALLBACK: R7 scan (proven) ====================
__global__ __launch_bounds__(512, 2) void lstm_scan_r7(
        const float* __restrict__ src, const float* __restrict__ bias,
        const float* __restrict__ c0,
        const unsigned short* __restrict__ Wh, const unsigned short* __restrict__ Wl,
        const unsigned short* __restrict__ Uh, const unsigned short* __restrict__ Ul,
        unsigned* __restrict__ hbuf, unsigned* __restrict__ cnt,
        float* __restrict__ out){
    const int tid  = threadIdx.x;
    const int cg   = blockIdx.x;
    const int lane = tid & 63;
    const int w    = tid >> 6;
    const int bt   = w >> 2;
    const int kq   = w & 3;
    const int lc   = lane & 15;
    const int kgrp = lane >> 4;
    const int row  = bt * 16 + lc;

    __shared__ float z_lds[4][BATCH][65];

    const int cb  = tid >> 4;
    const int chc = tid & 15;
    const int col = cg * 16 + chc;
    float c_state = c0[(size_t)cb * HDIM + col];
    float bias_g[4];
    #pragma unroll
    for (int g = 0; g < 4; g++) bias_g[g] = bias[g * HDIM + col];

    const uint4* WhF = reinterpret_cast<const uint4*>(Wh) + (size_t)cg * 4096;
    const uint4* WlF = reinterpret_cast<const uint4*>(Wl) + (size_t)cg * 4096;
    const uint4* UhF = reinterpret_cast<const uint4*>(Uh) + (size_t)cg * 4096;
    const uint4* UlF = reinterpret_cast<const uint4*>(Ul) + (size_t)cg * 4096;

    f32x4 acc[4];
    #pragma unroll
    for (int ct = 0; ct < 4; ct++)
        #pragma unroll
        for (int r = 0; r < 4; r++) acc[ct][r] = 0.f;

    auto phaseA = [&](int t){
        #pragma unroll
        for (int i = 0; i < 4; i++){
            int kb = kq * 4 + i;
            const float* xp = src + ((size_t)row * T_STEPS + t) * EDIM + kb * 32 + kgrp * 8;
            float xv[8];
            *reinterpret_cast<float4*>(&xv[0]) = *reinterpret_cast<const float4*>(xp);
            *reinterpret_cast<float4*>(&xv[4]) = *reinterpret_cast<const float4*>(xp + 4);
            bf16x8 ah, al;
            #pragma unroll
            for (int j = 0; j < 8; j++){
                unsigned short hi = f2bf(xv[j]);
                ah[j] = (short)hi;
                al[j] = (short)f2bf(xv[j] - bf2f(hi));
            }
            #pragma unroll
            for (int ct = 0; ct < 4; ct++){
                uint4 bh4 = WhF[kb * 256 + ct * 64 + lane];
                uint4 bl4 = WlF[kb * 256 + ct * 64 + lane];
                bf16x8 bh = *reinterpret_cast<bf16x8*>(&bh4);
                bf16x8 bl = *reinterpret_cast<bf16x8*>(&bl4);
                acc[ct] = __builtin_amdgcn_mfma_f32_16x16x32_bf16(ah, bh, acc[ct], 0, 0, 0);
                acc[ct] = __builtin_amdgcn_mfma_f32_16x16x32_bf16(ah, bl, acc[ct], 0, 0, 0);
                acc[ct] = __builtin_amdgcn_mfma_f32_16x16x32_bf16(al, bh, acc[ct], 0, 0, 0);
            }
        }
    };

    phaseA(0);

    for (int t = 0; t < T_STEPS; t++){
        if (t > 0){
            if (w == 0){
                const unsigned need = 32u * (unsigned)((t + 1) >> 1);
                while (__hip_atomic_load(&cnt[t & 1], __ATOMIC_RELAXED, __HIP_MEMORY_SCOPE_AGENT) < need)
                    __builtin_amdgcn_s_sleep(1);
            }
            __syncthreads();
        }

        const u64t* hp = reinterpret_cast<const u64t*>(hbuf)
                       + (size_t)(t & 1) * 8192 + (size_t)row * 256;
        u64t hv[16];
        #pragma unroll
        for (int i = 0; i < 4; i++){
            int base = (kq * 4 + i) * 16 + kgrp * 4;
            #pragma unroll
            for (int jp = 0; jp < 4; jp++)
                hv[i * 4 + jp] = __hip_atomic_load(hp + base + jp,
                                                   __ATOMIC_RELAXED, __HIP_MEMORY_SCOPE_AGENT);
        }

        #pragma unroll
        for (int i = 0; i < 4; i++){
            int kb = kq * 4 + i;
            bf16x8 ah, al;
            #pragma unroll
            for (int jp = 0; jp < 4; jp++){
                u64t q = hv[i * 4 + jp];
                unsigned a = (unsigned)q;
                unsigned b = (unsigned)(q >> 32);
                ah[jp * 2    ] = (short)(a & 0xffffu); al[jp * 2    ] = (short)(a >> 16);
                ah[jp * 2 + 1] = (short)(b & 0xffffu); al[jp * 2 + 1] = (short)(b >> 16);
            }
            #pragma unroll
            for (int ct = 0; ct < 4; ct++){
                uint4 uh4 = UhF[kb * 256 + ct * 64 + lane];
                uint4 ul4 = UlF[kb * 256 + ct * 64 + lane];
                bf16x8 uh = *reinterpret_cast<bf16x8*>(&uh4);
                bf16x8 ul = *reinterpret_cast<bf16x8*>(&ul4);
                acc[ct] = __builtin_amdgcn_mfma_f32_16x16x32_bf16(ah, uh, acc[ct], 0, 0, 0);
                acc[ct] = __builtin_amdgcn_mfma_f32_16x16x32_bf16(ah, ul, acc[ct], 0, 0, 0);
                acc[ct] = __builtin_amdgcn_mfma_f32_16x16x32_bf16(al, uh, acc[ct], 0, 0, 0);
            }
        }

        #pragma unroll
        for (int ct = 0; ct < 4; ct++)
            #pragma unroll
            for (int r = 0; r < 4; r++)
                z_lds[kq][bt * 16 + kgrp * 4 + r][ct * 16 + lc] = acc[ct][r];
        __syncthreads();

        {
            float z[4];
            #pragma unroll
            for (int g = 0; g < 4; g++)
                z[g] = z_lds[0][cb][g * 16 + chc] + z_lds[1][cb][g * 16 + chc]
                     + z_lds[2][cb][g * 16 + chc] + z_lds[3][cb][g * 16 + chc] + bias_g[g];
            float ig = 1.f / (1.f + __expf(-z[0]));
            float fg = 1.f / (1.f + __expf(-z[1]));
            float gg = tanhf(z[2]);
            float og = 1.f / (1.f + __expf(-z[3]));
            float cn = fg * c_state + ig * gg;
            c_state = cn;
            float hn = og * tanhf(cn);
            out[16384 + ((size_t)t * BATCH + cb) * HDIM + col] = hn;
            if (t == T_STEPS - 1){
                out[(size_t)cb * HDIM + col] = hn;
                out[16384 + (size_t)T_STEPS * BATCH * HDIM + (size_t)cb * HDIM + col] = hn;
            }
            unsigned short hi = f2bf(hn);
            unsigned short lo = f2bf(hn - bf2f(hi));
            __hip_atomic_store(&hbuf[(size_t)((t + 1) & 1) * (BATCH * HDIM) + (size_t)cb * HDIM + col],
                               (unsigned)hi | ((unsigned)lo << 16),
                               __ATOMIC_RELAXED, __HIP_MEMORY_SCOPE_AGENT);
        }
        __syncthreads();
        if (tid == 0)
            __hip_atomic_fetch_add(&cnt[(t + 1) & 1], 1u,
                                   __ATOMIC_RELAXED, __HIP_MEMORY_SCOPE_AGENT);

        #pragma unroll
        for (int ct = 0; ct < 4; ct++)
            #pragma unroll
            for (int r = 0; r < 4; r++) acc[ct][r] = 0.f;
        if (t + 1 < T_STEPS) phaseA(t + 1);
    }
}

// ============================ LAUNCH =======================================
extern "C" void kernel_launch(void* const* d_in, const int* in_sizes, int n_in,
                              void* d_out, int out_size, void* d_ws, size_t ws_size,
                              hipStream_t stream){
    const float* src = (const float*)d_in[0];
    const float* W   = (const float*)d_in[1];
    const float* U   = (const float*)d_in[2];
    const float* b   = (const float*)d_in[3];
    const float* h0  = (const float*)d_in[4];
    const float* c0  = (const float*)d_in[5];
    float* out = (float*)d_out;
    char* ws = (char*)d_ws;

    int TCH = 0;
    const int cand[5] = {256, 128, 64, 32, 16};
    for (int i = 0; i < 5; i++){
        if (FIXED_WS + (size_t)cand[i] * 262144ull <= ws_size){ TCH = cand[i]; break; }
    }

    if (TCH > 0){
        unsigned*       hbuf = (unsigned*)(ws);
        unsigned*       cnt  = (unsigned*)(ws + 0x020000ull);
        float*          c_ws = (float*)(ws + 0x021000ull);
        unsigned short* Wh   = (unsigned short*)(ws + 0x031000ull);
        unsigned short* Wl   = (unsigned short*)(ws + 0x231000ull);
        unsigned short* Uh   = (unsigned short*)(ws + 0x431000ull);
        unsigned short* Ul   = (unsigned short*)(ws + 0x631000ull);
        float*          xWc  = (float*)(ws + FIXED_WS);

        hipMemsetAsync(cnt, 0, 8, stream);
        prep_kernel<<<1024, 256, 0, stream>>>(W, U, h0, Wh, Wl, Uh, Ul, hbuf);
        const int nch = T_STEPS / TCH;
        for (int i = 0; i < nch; i++){
            int t0 = i * TCH;
            xw_gemm_chunk<<<(TCH / 4) * 32, 256, 0, stream>>>(src, Wh, Wl, xWc, t0);
            lstm_scan_fast<<<32, 512, 0, stream>>>(b, c0, Uh, Ul, hbuf, cnt,
                                                   xWc, c_ws, out, t0, TCH);
        }
    } else {
        unsigned*       hbuf = (unsigned*)(ws);
        unsigned*       cnt  = (unsigned*)(ws + 0x20000);
        unsigned short* Wh   = (unsigned short*)(ws + 0x21000);
        unsigned short* Wl   = Wh + 1048576;
        unsigned short* Uh   = Wl + 1048576;
        unsigned short* Ul   = Uh + 1048576;
        hipMemsetAsync(cnt, 0, 8, stream);
        prep_kernel<<<1024, 256, 0, stream>>>(W, U, h0, Wh, Wl, Uh, Ul, hbuf);
        lstm_scan_r7<<<32, 512, 0, stream>>>(src, b, c0, Wh, Wl, Uh, Ul, hbuf, cnt, out);
    }
}